// Round 10
// baseline (246.634 us; speedup 1.0000x reference)
//
#include <hip/hip_runtime.h>

#define NN 4096
#define DD 128
#define REGC 0.05f
#define EPSC 1e-8f
#define NSINK 2
#define KPAD2 136   // shorts; 272B row stride, keeps 16B row alignment

typedef float f32x4 __attribute__((ext_vector_type(4)));
typedef float f32x2 __attribute__((ext_vector_type(2)));
typedef short s16x8 __attribute__((ext_vector_type(8)));
typedef short s16x4 __attribute__((ext_vector_type(4)));

__device__ __forceinline__ float wave_reduce_sum(float s) {
#pragma unroll
  for (int m = 32; m >= 1; m >>= 1) s += __shfl_xor(s, m, 64);
  return s;
}

__device__ __forceinline__ short f32_to_bf16(float f) {
  union { float f; unsigned u; } x; x.f = f;
  unsigned r = (x.u + 0x7FFFu + ((x.u >> 16) & 1u)) >> 16;
  return (short)r;
}

__device__ __forceinline__ void fp8x4_decode(unsigned int k, float* o) {
  f32x2 lo = __builtin_amdgcn_cvt_pk_f32_fp8((int)k, false);
  f32x2 hi = __builtin_amdgcn_cvt_pk_f32_fp8((int)k, true);
  o[0] = lo[0]; o[1] = lo[1]; o[2] = hi[0]; o[3] = hi[1];
}

__device__ __forceinline__ void fp8x16_decode(uint4 k, float* o) {
  fp8x4_decode(k.x, o); fp8x4_decode(k.y, o + 4);
  fp8x4_decode(k.z, o + 8); fp8x4_decode(k.w, o + 12);
}

__device__ __forceinline__ float dot16v(uint4 k, f32x4 v0, f32x4 v1, f32x4 v2, f32x4 v3) {
  float o[16];
  fp8x16_decode(k, o);
  float s = 0.f;
#pragma unroll
  for (int j = 0; j < 4; j++) s += o[j] * v0[j];
#pragma unroll
  for (int j = 0; j < 4; j++) s += o[4 + j] * v1[j];
#pragma unroll
  for (int j = 0; j < 4; j++) s += o[8 + j] * v2[j];
#pragma unroll
  for (int j = 0; j < 4; j++) s += o[12 + j] * v3[j];
  return s;
}

// dual accumulate: s1 += K*v, s2 += K*v*ln(K)   (loss C = -REG*lnK factored out)
__device__ __forceinline__ void dot16v_dual(uint4 k, f32x4 v0, f32x4 v1, f32x4 v2, f32x4 v3,
                                            float& s1, float& s2) {
  float o[16];
  fp8x16_decode(k, o);
#pragma unroll
  for (int q = 0; q < 4; q++) {
    f32x4 vv = (q == 0) ? v0 : (q == 1) ? v1 : (q == 2) ? v2 : v3;
#pragma unroll
    for (int j = 0; j < 4; j++) {
      float kf = o[q * 4 + j];
      float kv = kf * vv[j];
      s1 += kv;
      s2 += kv * __logf(fmaxf(kf, 1e-6f));
    }
  }
}

// async global->LDS, 16B per lane; LDS slot = uniform base + lane*16
__device__ __forceinline__ void async_ld16(const unsigned char* g, unsigned char* l) {
  __builtin_amdgcn_global_load_lds((const __attribute__((address_space(1))) void*)g,
                                   (__attribute__((address_space(3))) void*)l, 16, 0, 0);
}

// wait this wave's own vmem (incl. global_load_lds) to 0; ignore lgkm/exp
__device__ __forceinline__ void wave_vm_drain() {
  __builtin_amdgcn_s_waitcnt(0x0f70);   // vmcnt=0, expcnt=7, lgkmcnt=15
}

// grid 1536, block 256: 8 rows/block, 32 lanes/row, f32x4 loads; row norms + bf16 convert
__global__ __launch_bounds__(256) void prep_kernel(const float* __restrict__ z0, const float* __restrict__ z1,
                                                   const float* __restrict__ z2, short* __restrict__ zb,
                                                   float* __restrict__ sq) {
  int tid = threadIdx.x;
  int row = blockIdx.x * 8 + (tid >> 5);
  int e = (tid & 31) * 4;
  int zi = row >> 12;
  const float* z = (zi == 0) ? z0 : ((zi == 1) ? z1 : z2);
  int r = row & (NN - 1);
  f32x4 val = *(const f32x4*)&z[r * DD + e];
  s16x4 b;
#pragma unroll
  for (int j = 0; j < 4; j++) b[j] = f32_to_bf16(val[j]);
  *(s16x4*)&zb[row * DD + e] = b;
  float s = val[0] * val[0] + val[1] * val[1] + val[2] * val[2] + val[3] * val[3];
#pragma unroll
  for (int m = 16; m >= 1; m >>= 1) s += __shfl_xor(s, m, 64);
  if ((tid & 31) == 0) sq[row] = s;
}

// grid dim3(32,32,3), block 256. K rows = x (blockIdx.y), K cols = y (blockIdx.x).
// A operand = y (LDS), B operand = x (global) -> lane's 4 acc regs horizontal in K ->
// pack u32 -> DIRECT u32 global stores (no LDS transpose). Col sums -> cpart.
__global__ __launch_bounds__(256, 4) void kbuild_kernel(const short* __restrict__ zb, const float* __restrict__ sq,
                                                        unsigned char* __restrict__ K, float* __restrict__ cpart) {
  int p = blockIdx.z;
  int ai = (p == 2) ? 1 : 0;            // pairs (0,1),(0,2),(1,2)
  int bi = (p == 0) ? 1 : 2;
  const short* xg = zb + ai * NN * DD + blockIdx.y * 128 * DD;   // B operand (K rows)
  const short* yg = zb + bi * NN * DD + blockIdx.x * 128 * DD;   // A operand (K cols), staged
  const float* sqx = sq + ai * NN + blockIdx.y * 128;
  const float* sqy = sq + bi * NN + blockIdx.x * 128;
  __shared__ __align__(16) short ys[128 * KPAD2];
  __shared__ float colsum[128];
  int tid = threadIdx.x;
  for (int i = tid; i < 2048; i += 256) {
    int row = i >> 4, seg = i & 15;
    *(uint4*)&ys[row * KPAD2 + seg * 8] = *(const uint4*)&yg[row * DD + seg * 8];
  }
  if (tid < 128) colsum[tid] = 0.f;
  __syncthreads();
  int w = tid >> 6, lane = tid & 63;
  int wy = (w >> 1) * 64, wx = (w & 1) * 64;   // y(col) / x(row) quadrants
  int lrow = lane & 15, lk = lane >> 4;
  f32x4 acc[4][4];   // [yt][xt]
#pragma unroll
  for (int i = 0; i < 4; i++)
#pragma unroll
    for (int j = 0; j < 4; j++) acc[i][j] = (f32x4){0.f, 0.f, 0.f, 0.f};
#pragma unroll
  for (int kk = 0; kk < 4; kk++) {
    s16x8 a[4], b[4];
#pragma unroll
    for (int t = 0; t < 4; t++) {
      a[t] = *(const s16x8*)&ys[(wy + t * 16 + lrow) * KPAD2 + kk * 32 + lk * 8];
      b[t] = *(const s16x8*)&xg[(wx + t * 16 + lrow) * DD + kk * 32 + lk * 8];
    }
#pragma unroll
    for (int yt = 0; yt < 4; yt++)
#pragma unroll
      for (int xt = 0; xt < 4; xt++)
        acc[yt][xt] = __builtin_amdgcn_mfma_f32_16x16x32_bf16(a[yt], b[xt], acc[yt][xt], 0, 0, 0);
  }
  // D layout: lane&15 -> x (K-row); (lane>>4)*4+reg -> y (K-col). pk = 4 consecutive cols.
  unsigned char* Kb = K + (size_t)p * NN * NN + (size_t)blockIdx.y * 128 * NN + blockIdx.x * 128;
  float csum[4][4];   // [yt][r]
#pragma unroll
  for (int i = 0; i < 4; i++)
#pragma unroll
    for (int j = 0; j < 4; j++) csum[i][j] = 0.f;
#pragma unroll
  for (int xt = 0; xt < 4; xt++) {
    int xl = wx + xt * 16 + lrow;
    float sx = sqx[xl];
#pragma unroll
    for (int yt = 0; yt < 4; yt++) {
      int yl0 = wy + yt * 16 + lk * 4;
      float kf[4];
#pragma unroll
      for (int r = 0; r < 4; r++) {
        float Cv = fmaxf(sx + sqy[yl0 + r] - 2.0f * acc[yt][xt][r], 0.0f);
        kf[r] = __expf(Cv * (-1.0f / REGC));
        csum[yt][r] += kf[r];
      }
      int pw = __builtin_amdgcn_cvt_pk_fp8_f32(kf[0], kf[1], 0, false);
      pw = __builtin_amdgcn_cvt_pk_fp8_f32(kf[2], kf[3], pw, true);
      *(unsigned int*)(Kb + (size_t)xl * NN + yl0) = (unsigned int)pw;
    }
  }
#pragma unroll
  for (int yt = 0; yt < 4; yt++)
#pragma unroll
    for (int r = 0; r < 4; r++) {
      float s = csum[yt][r];
      s += __shfl_xor(s, 1, 64); s += __shfl_xor(s, 2, 64);
      s += __shfl_xor(s, 4, 64); s += __shfl_xor(s, 8, 64);
      if (lrow == 0) atomicAdd(&colsum[wy + yt * 16 + lk * 4 + r], s);
    }
  __syncthreads();
  if (tid < 128)
    cpart[(size_t)(p * 32 + blockIdx.y) * NN + blockIdx.x * 128 + tid] = colsum[tid];
}

// grid dim3(16,3), block 256: v = nu/(sum_by cpart + eps)  (initial v for u0=1)
__global__ __launch_bounds__(256) void vinit_kernel(const float* __restrict__ cpart, float* __restrict__ v) {
  int p = blockIdx.y;
  int col = blockIdx.x * 256 + threadIdx.x;
  float s = 0.f;
#pragma unroll 8
  for (int by = 0; by < 32; by++) s += cpart[(size_t)(p * 32 + by) * NN + col];
  v[p * NN + col] = (1.0f / NN) * __builtin_amdgcn_rcpf(s + EPSC);
}

// grid 1536 (p*512+rb), block 256 (4 waves), 8 rows/block:
//   A: wave w async-DMAs ITS OWN 2 rows (8 KB) into LDS, then waits only its own vmcnt
//   B: u = mu/(K v + eps) for rows 2w,2w+1 (v from global, L1/L2-hot)
//   C: (after barrier) thread owns 16 cols over 8 rows; partial stored vcalc-transposed
__global__ __launch_bounds__(256, 4) void sink_fused(const unsigned char* __restrict__ K,
                                                     const float* __restrict__ v, float* __restrict__ partial) {
  int bid = blockIdx.x;
  int p = bid >> 9;
  int rb = bid & 511;
  int tid = threadIdx.x, w = tid >> 6, lane = tid & 63;
  __shared__ __align__(16) unsigned char ks[8 * NN];
  __shared__ float ulds[8];
  const unsigned char* Kp = K + (size_t)p * NN * NN;
  int r0 = rb * 8;
  {
    const unsigned char* g = Kp + (size_t)r0 * NN + w * 8192 + lane * 16;
#pragma unroll
    for (int i = 0; i < 8; i++)
      async_ld16(g + i * 1024, &ks[w * 8192 + i * 1024]);
  }
  wave_vm_drain();   // own rows landed; no block barrier needed for phase B
  const float* vp = v + p * NN;
  {
    float acc0 = 0.f, acc1 = 0.f;
#pragma unroll
    for (int c = 0; c < 4; c++) {
      uint4 k0 = *(const uint4*)&ks[(2 * w) * NN + c * 1024 + lane * 16];
      uint4 k1 = *(const uint4*)&ks[(2 * w + 1) * NN + c * 1024 + lane * 16];
      const float* vb = vp + c * 1024 + lane * 16;
      f32x4 v0 = *(const f32x4*)(vb + 0);
      f32x4 v1 = *(const f32x4*)(vb + 4);
      f32x4 v2 = *(const f32x4*)(vb + 8);
      f32x4 v3 = *(const f32x4*)(vb + 12);
      acc0 += dot16v(k0, v0, v1, v2, v3);
      acc1 += dot16v(k1, v0, v1, v2, v3);
    }
    acc0 = wave_reduce_sum(acc0);
    acc1 = wave_reduce_sum(acc1);
    if (lane == 0) {
      ulds[2 * w] = (1.0f / NN) / (acc0 + EPSC);
      ulds[2 * w + 1] = (1.0f / NN) / (acc1 + EPSC);
    }
  }
  __syncthreads();   // phase C reads all 8 rows + ulds
  float ca[16];
#pragma unroll
  for (int j = 0; j < 16; j++) ca[j] = 0.f;
#pragma unroll
  for (int r = 0; r < 8; r++) {
    uint4 k = *(const uint4*)&ks[r * NN + tid * 16];
    float kd[16];
    fp8x16_decode(k, kd);
    float ur = ulds[r];
#pragma unroll
    for (int j = 0; j < 16; j++) ca[j] += kd[j] * ur;
  }
  float* pd = partial + (((size_t)p * 256 + tid) * 512 + rb) * 16;
#pragma unroll
  for (int q = 0; q < 4; q++)
    *(f32x4*)&pd[q * 4] = (f32x4){ca[q * 4], ca[q * 4 + 1], ca[q * 4 + 2], ca[q * 4 + 3]};
}

// grid dim3(256,3), block 256: col-chunk cc owns 16 cols; 512 summand-chunks contiguous (32 KB)
__global__ __launch_bounds__(256) void vcalc_kernel(const float* __restrict__ partial, float* __restrict__ v) {
  int p = blockIdx.y;
  int cc = blockIdx.x;
  int tid = threadIdx.x, w = tid >> 6, lane = tid & 63;
  const float* base = partial + ((size_t)p * 256 + cc) * 512 * 16;
  f32x4 a0 = {0.f, 0.f, 0.f, 0.f}, a1 = a0, a2 = a0, a3 = a0;
#pragma unroll 2
  for (int i = tid; i < 512; i += 256) {
    const float* q = base + (size_t)i * 16;
    a0 += *(const f32x4*)(q + 0);
    a1 += *(const f32x4*)(q + 4);
    a2 += *(const f32x4*)(q + 8);
    a3 += *(const f32x4*)(q + 12);
  }
#pragma unroll
  for (int m = 32; m >= 1; m >>= 1) {
#pragma unroll
    for (int j = 0; j < 4; j++) {
      a0[j] += __shfl_xor(a0[j], m, 64);
      a1[j] += __shfl_xor(a1[j], m, 64);
      a2[j] += __shfl_xor(a2[j], m, 64);
      a3[j] += __shfl_xor(a3[j], m, 64);
    }
  }
  __shared__ float red[4][16];
  if (lane == 0) {
#pragma unroll
    for (int j = 0; j < 4; j++) {
      red[w][j] = a0[j]; red[w][4 + j] = a1[j];
      red[w][8 + j] = a2[j]; red[w][12 + j] = a3[j];
    }
  }
  __syncthreads();
  if (tid < 16) {
    float s = red[0][tid] + red[1][tid] + red[2][tid] + red[3][tid];
    v[p * NN + cc * 16 + tid] = (1.0f / NN) * __builtin_amdgcn_rcpf(s + EPSC);
  }
}

// grid 1536 (p*512+rb), block 256, 8 rows/block, single pass, NO block barrier in hot path:
//   per row: s1 = K·v, s2 = K·v·lnK; u = mu/(s1+eps); loss_row = u*(-REG)*s2
__global__ __launch_bounds__(256, 4) void loss_fused(const unsigned char* __restrict__ K,
                                                     const float* __restrict__ v, float* __restrict__ out) {
  int bid = blockIdx.x;
  int p = bid >> 9;
  int rb = bid & 511;
  int tid = threadIdx.x, w = tid >> 6, lane = tid & 63;
  __shared__ __align__(16) unsigned char ks[8 * NN];
  const unsigned char* Kp = K + (size_t)p * NN * NN;
  int r0 = rb * 8;
  {
    const unsigned char* g = Kp + (size_t)r0 * NN + w * 8192 + lane * 16;
#pragma unroll
    for (int i = 0; i < 8; i++)
      async_ld16(g + i * 1024, &ks[w * 8192 + i * 1024]);
  }
  wave_vm_drain();   // wave-private rows; no barrier
  const float* vp = v + p * NN;
  float s1a = 0.f, s2a = 0.f, s1b = 0.f, s2b = 0.f;
#pragma unroll
  for (int c = 0; c < 4; c++) {
    uint4 k0 = *(const uint4*)&ks[(2 * w) * NN + c * 1024 + lane * 16];
    uint4 k1 = *(const uint4*)&ks[(2 * w + 1) * NN + c * 1024 + lane * 16];
    const float* vb = vp + c * 1024 + lane * 16;
    f32x4 v0 = *(const f32x4*)(vb + 0);
    f32x4 v1 = *(const f32x4*)(vb + 4);
    f32x4 v2 = *(const f32x4*)(vb + 8);
    f32x4 v3 = *(const f32x4*)(vb + 12);
    dot16v_dual(k0, v0, v1, v2, v3, s1a, s2a);
    dot16v_dual(k1, v0, v1, v2, v3, s1b, s2b);
  }
  s1a = wave_reduce_sum(s1a);
  s2a = wave_reduce_sum(s2a);
  s1b = wave_reduce_sum(s1b);
  s2b = wave_reduce_sum(s2b);
  float ua = (1.0f / NN) / (s1a + EPSC);
  float ub = (1.0f / NN) / (s1b + EPSC);
  float lt = ua * (-REGC) * s2a + ub * (-REGC) * s2b;
  __shared__ float red[4];
  if (lane == 0) red[w] = lt;
  __syncthreads();
  if (tid == 0) atomicAdd(out, (red[0] + red[1] + red[2] + red[3]) * (1.0f / 3.0f));
}

extern "C" void kernel_launch(void* const* d_in, const int* in_sizes, int n_in,
                              void* d_out, int out_size, void* d_ws, size_t ws_size,
                              hipStream_t stream) {
  const float* z0 = (const float*)d_in[0];
  const float* z1 = (const float*)d_in[1];
  const float* z2 = (const float*)d_in[2];
  float* out = (float*)d_out;
  char* ws = (char*)d_ws;

  const size_t K_BYTES = (size_t)3 * NN * NN;            // 50331648 (fp8)
  unsigned char* K = (unsigned char*)ws;
  short* zb = (short*)(ws + K_BYTES);                    // 3145728 B
  float* sq = (float*)(ws + K_BYTES + 3145728);          // 49152 B
  float* v = (float*)(ws + K_BYTES + 3145728 + 49152);   // 49152 B
  float* cpart = (float*)(ws + K_BYTES + 3145728 + 2 * 49152);   // 1572864 B
  float* partial = (float*)(ws + K_BYTES + 3145728 + 2 * 49152 + 1572864);  // 25.2 MB

  hipMemsetAsync(d_out, 0, sizeof(float), stream);

  prep_kernel<<<1536, 256, 0, stream>>>(z0, z1, z2, zb, sq);
  kbuild_kernel<<<dim3(32, 32, 3), 256, 0, stream>>>(zb, sq, K, cpart);
  vinit_kernel<<<dim3(16, 3), 256, 0, stream>>>(cpart, v);

  for (int it = 0; it < NSINK; it++) {
    sink_fused<<<1536, 256, 0, stream>>>(K, v, partial);
    vcalc_kernel<<<dim3(256, 3), 256, 0, stream>>>(partial, v);
  }
  // loss folds the final u-half-step (effectively NSINK + 0.5 iterations)
  loss_fused<<<1536, 256, 0, stream>>>(K, v, out);
}

// Round 11
// 205.982 us; speedup vs baseline: 1.1974x; 1.1974x over previous
//
#include <hip/hip_runtime.h>

#define NN 4096
#define DD 128
#define REGC 0.05f
#define EPSC 1e-8f
#define NSINK 2
#define KPAD2 136   // shorts; 272B row stride, keeps 16B row alignment

typedef float f32x4 __attribute__((ext_vector_type(4)));
typedef float f32x2 __attribute__((ext_vector_type(2)));
typedef short s16x8 __attribute__((ext_vector_type(8)));
typedef short s16x4 __attribute__((ext_vector_type(4)));

__device__ __forceinline__ float wave_reduce_sum(float s) {
#pragma unroll
  for (int m = 32; m >= 1; m >>= 1) s += __shfl_xor(s, m, 64);
  return s;
}

__device__ __forceinline__ short f32_to_bf16(float f) {
  union { float f; unsigned u; } x; x.f = f;
  unsigned r = (x.u + 0x7FFFu + ((x.u >> 16) & 1u)) >> 16;
  return (short)r;
}

__device__ __forceinline__ void fp8x4_decode(unsigned int k, float* o) {
  f32x2 lo = __builtin_amdgcn_cvt_pk_f32_fp8((int)k, false);
  f32x2 hi = __builtin_amdgcn_cvt_pk_f32_fp8((int)k, true);
  o[0] = lo[0]; o[1] = lo[1]; o[2] = hi[0]; o[3] = hi[1];
}

__device__ __forceinline__ void fp8x16_decode(uint4 k, float* o) {
  fp8x4_decode(k.x, o); fp8x4_decode(k.y, o + 4);
  fp8x4_decode(k.z, o + 8); fp8x4_decode(k.w, o + 12);
}

__device__ __forceinline__ float dot16v(uint4 k, f32x4 v0, f32x4 v1, f32x4 v2, f32x4 v3) {
  float o[16];
  fp8x16_decode(k, o);
  float s = 0.f;
#pragma unroll
  for (int j = 0; j < 4; j++) s += o[j] * v0[j];
#pragma unroll
  for (int j = 0; j < 4; j++) s += o[4 + j] * v1[j];
#pragma unroll
  for (int j = 0; j < 4; j++) s += o[8 + j] * v2[j];
#pragma unroll
  for (int j = 0; j < 4; j++) s += o[12 + j] * v3[j];
  return s;
}

// dual accumulate: s1 += K*v, s2 += K*v*ln(K)   (loss C = -REG*lnK factored out)
__device__ __forceinline__ void dot16v_dual(uint4 k, f32x4 v0, f32x4 v1, f32x4 v2, f32x4 v3,
                                            float& s1, float& s2) {
  float o[16];
  fp8x16_decode(k, o);
#pragma unroll
  for (int q = 0; q < 4; q++) {
    f32x4 vv = (q == 0) ? v0 : (q == 1) ? v1 : (q == 2) ? v2 : v3;
#pragma unroll
    for (int j = 0; j < 4; j++) {
      float kf = o[q * 4 + j];
      float kv = kf * vv[j];
      s1 += kv;
      s2 += kv * __logf(fmaxf(kf, 1e-6f));
    }
  }
}

// grid 1536, block 256: 8 rows/block, 32 lanes/row, f32x4 loads; row norms + bf16 convert
__global__ __launch_bounds__(256) void prep_kernel(const float* __restrict__ z0, const float* __restrict__ z1,
                                                   const float* __restrict__ z2, short* __restrict__ zb,
                                                   float* __restrict__ sq) {
  int tid = threadIdx.x;
  int row = blockIdx.x * 8 + (tid >> 5);
  int e = (tid & 31) * 4;
  int zi = row >> 12;
  const float* z = (zi == 0) ? z0 : ((zi == 1) ? z1 : z2);
  int r = row & (NN - 1);
  f32x4 val = *(const f32x4*)&z[r * DD + e];
  s16x4 b;
#pragma unroll
  for (int j = 0; j < 4; j++) b[j] = f32_to_bf16(val[j]);
  *(s16x4*)&zb[row * DD + e] = b;
  float s = val[0] * val[0] + val[1] * val[1] + val[2] * val[2] + val[3] * val[3];
#pragma unroll
  for (int m = 16; m >= 1; m >>= 1) s += __shfl_xor(s, m, 64);
  if ((tid & 31) == 0) sq[row] = s;
}

// grid dim3(32,32,3), block 256. K rows = x (blockIdx.y), K cols = y (blockIdx.x).
// A operand = y (LDS), B operand = x (global) -> lane's 4 acc regs horizontal in K ->
// pack u32 -> padded LDS tile (kt, aliased over ys) -> full-line uint4 stores.
// Col sums -> cpart[(p*32+by)*NN + bx*128+col].  [round-9 version: 54 us measured]
__global__ __launch_bounds__(256, 3) void kbuild_kernel(const short* __restrict__ zb, const float* __restrict__ sq,
                                                        unsigned char* __restrict__ K, float* __restrict__ cpart) {
  int p = blockIdx.z;
  int ai = (p == 2) ? 1 : 0;            // pairs (0,1),(0,2),(1,2)
  int bi = (p == 0) ? 1 : 2;
  const short* xg = zb + ai * NN * DD + blockIdx.y * 128 * DD;   // B operand (K rows)
  const short* yg = zb + bi * NN * DD + blockIdx.x * 128 * DD;   // A operand (K cols), staged
  const float* sqx = sq + ai * NN + blockIdx.y * 128;
  const float* sqy = sq + bi * NN + blockIdx.x * 128;
  __shared__ __align__(16) unsigned char smem[128 * KPAD2 * 2];  // ys, later aliased by kt
  __shared__ float colsum[128];
  short* ys = (short*)smem;
  unsigned int* kt = (unsigned int*)smem;   // [128][36] u32, row stride 144B
  int tid = threadIdx.x;
  for (int i = tid; i < 2048; i += 256) {
    int row = i >> 4, seg = i & 15;
    *(uint4*)&ys[row * KPAD2 + seg * 8] = *(const uint4*)&yg[row * DD + seg * 8];
  }
  if (tid < 128) colsum[tid] = 0.f;
  __syncthreads();
  int w = tid >> 6, lane = tid & 63;
  int wy = (w >> 1) * 64, wx = (w & 1) * 64;   // y(col) / x(row) quadrants
  int lrow = lane & 15, lk = lane >> 4;
  f32x4 acc[4][4];   // [yt][xt]
#pragma unroll
  for (int i = 0; i < 4; i++)
#pragma unroll
    for (int j = 0; j < 4; j++) acc[i][j] = (f32x4){0.f, 0.f, 0.f, 0.f};
#pragma unroll
  for (int kk = 0; kk < 4; kk++) {
    s16x8 a[4], b[4];
#pragma unroll
    for (int t = 0; t < 4; t++) {
      a[t] = *(const s16x8*)&ys[(wy + t * 16 + lrow) * KPAD2 + kk * 32 + lk * 8];
      b[t] = *(const s16x8*)&xg[(wx + t * 16 + lrow) * DD + kk * 32 + lk * 8];
    }
#pragma unroll
    for (int yt = 0; yt < 4; yt++)
#pragma unroll
      for (int xt = 0; xt < 4; xt++)
        acc[yt][xt] = __builtin_amdgcn_mfma_f32_16x16x32_bf16(a[yt], b[xt], acc[yt][xt], 0, 0, 0);
  }
  unsigned int pk[4][4];   // [xt][yt] packed 4 consecutive K-cols
  float csum[4][4];        // [yt][r]
#pragma unroll
  for (int i = 0; i < 4; i++)
#pragma unroll
    for (int j = 0; j < 4; j++) csum[i][j] = 0.f;
#pragma unroll
  for (int xt = 0; xt < 4; xt++) {
    int xl = wx + xt * 16 + lrow;
    float sx = sqx[xl];
#pragma unroll
    for (int yt = 0; yt < 4; yt++) {
      int yl0 = wy + yt * 16 + lk * 4;
      float kf[4];
#pragma unroll
      for (int r = 0; r < 4; r++) {
        float Cv = fmaxf(sx + sqy[yl0 + r] - 2.0f * acc[yt][xt][r], 0.0f);
        kf[r] = __expf(Cv * (-1.0f / REGC));
        csum[yt][r] += kf[r];
      }
      int pw = __builtin_amdgcn_cvt_pk_fp8_f32(kf[0], kf[1], 0, false);
      pw = __builtin_amdgcn_cvt_pk_fp8_f32(kf[2], kf[3], pw, true);
      pk[xt][yt] = (unsigned int)pw;
    }
  }
#pragma unroll
  for (int yt = 0; yt < 4; yt++)
#pragma unroll
    for (int r = 0; r < 4; r++) {
      float s = csum[yt][r];
      s += __shfl_xor(s, 1, 64); s += __shfl_xor(s, 2, 64);
      s += __shfl_xor(s, 4, 64); s += __shfl_xor(s, 8, 64);
      if (lrow == 0) atomicAdd(&colsum[wy + yt * 16 + lk * 4 + r], s);
    }
  __syncthreads();   // done reading ys; safe to alias with kt
#pragma unroll
  for (int xt = 0; xt < 4; xt++) {
    int xl = wx + xt * 16 + lrow;
#pragma unroll
    for (int yt = 0; yt < 4; yt++)
      kt[xl * 36 + ((wy + yt * 16) >> 2) + lk] = pk[xt][yt];
  }
  __syncthreads();
  unsigned char* Kb = K + (size_t)p * NN * NN + (size_t)blockIdx.y * 128 * NN + blockIdx.x * 128;
#pragma unroll
  for (int rd = 0; rd < 4; rd++) {
    int rl = (tid >> 3) + rd * 32;
    int ch = tid & 7;
    uint4 d = *(const uint4*)&kt[rl * 36 + ch * 4];
    *(uint4*)(Kb + (size_t)rl * NN + ch * 16) = d;
  }
  if (tid < 128)
    cpart[(size_t)(p * 32 + blockIdx.y) * NN + blockIdx.x * 128 + tid] = colsum[tid];
}

// grid dim3(16,3), block 256: t_part chunk0 = sum_by cpart (= K^T 1), chunk1 = 0
__global__ __launch_bounds__(256) void tinit_kernel(const float* __restrict__ cpart, float* __restrict__ t_part) {
  int p = blockIdx.y;
  int col = blockIdx.x * 256 + threadIdx.x;
  float s = 0.f;
#pragma unroll 8
  for (int by = 0; by < 32; by++) s += cpart[(size_t)(p * 32 + by) * NN + col];
  t_part[(size_t)p * NN + col] = s;
  t_part[(size_t)(3 + p) * NN + col] = 0.f;
}

// grid 768 (p*256+rb), block 256, 16 rows/block [round-5 version, ~15 us]:
//   A: v = nu/(t_part[0]+t_part[1]+eps) -> LDS (swizzled)
//   B: u = mu/(K v + eps) for the block's 16 rows (4 rows/wave), direct global K reads
__global__ __launch_bounds__(256) void sink_u(const unsigned char* __restrict__ K,
                                              const float* __restrict__ t_part, float* __restrict__ u) {
  int bid = blockIdx.x;
  int p = bid >> 8;
  int rb = bid & 255;
  int tid = threadIdx.x;
  int w = tid >> 6, lane = tid & 63;
  __shared__ float vswz[NN];   // v[col], col = c*1024 + lane*16 + q*4 + j at [((c*4+q)*64+lane)*4+j]
  {
    int c = tid >> 6;
#pragma unroll
    for (int q = 0; q < 4; q++) {
      int idx = c * 1024 + lane * 16 + q * 4;
      f32x4 ta = *(const f32x4*)&t_part[(size_t)p * NN + idx];
      f32x4 tb = *(const f32x4*)&t_part[(size_t)(3 + p) * NN + idx];
      f32x4 o;
#pragma unroll
      for (int j = 0; j < 4; j++) o[j] = (1.0f / NN) * __builtin_amdgcn_rcpf(ta[j] + tb[j] + EPSC);
      *(f32x4*)&vswz[((c * 4 + q) * 64 + lane) * 4] = o;
    }
  }
  __syncthreads();
  const unsigned char* Kp = K + (size_t)p * NN * NN;
  int r0 = rb * 16;
  const unsigned char* kbase = Kp + (size_t)(r0 + w * 4) * NN + lane * 16;
  float acc0 = 0.f, acc1 = 0.f, acc2 = 0.f, acc3 = 0.f;
#pragma unroll
  for (int c = 0; c < 4; c++) {
    uint4 k0 = *(const uint4*)(kbase + c * 1024);
    uint4 k1 = *(const uint4*)(kbase + (size_t)NN + c * 1024);
    uint4 k2 = *(const uint4*)(kbase + (size_t)2 * NN + c * 1024);
    uint4 k3 = *(const uint4*)(kbase + (size_t)3 * NN + c * 1024);
    f32x4 v0 = *(const f32x4*)&vswz[((c * 4 + 0) * 64 + lane) * 4];
    f32x4 v1 = *(const f32x4*)&vswz[((c * 4 + 1) * 64 + lane) * 4];
    f32x4 v2 = *(const f32x4*)&vswz[((c * 4 + 2) * 64 + lane) * 4];
    f32x4 v3 = *(const f32x4*)&vswz[((c * 4 + 3) * 64 + lane) * 4];
    acc0 += dot16v(k0, v0, v1, v2, v3);
    acc1 += dot16v(k1, v0, v1, v2, v3);
    acc2 += dot16v(k2, v0, v1, v2, v3);
    acc3 += dot16v(k3, v0, v1, v2, v3);
  }
  acc0 = wave_reduce_sum(acc0);
  acc1 = wave_reduce_sum(acc1);
  acc2 = wave_reduce_sum(acc2);
  acc3 = wave_reduce_sum(acc3);
  if (lane == 0) {
    float* ug = u + p * NN + r0 + w * 4;
    ug[0] = (1.0f / NN) / (acc0 + EPSC);
    ug[1] = (1.0f / NN) / (acc1 + EPSC);
    ug[2] = (1.0f / NN) / (acc2 + EPSC);
    ug[3] = (1.0f / NN) / (acc3 + EPSC);
  }
}

// grid dim3(64,2,3), block 256 [round-5 version, ~15 us]: column pass, NO atomics.
// t_part[(chunk*3+p)*NN + cols] = sum over chunk's 2048 rows of K[row][col]*u[row]
__global__ __launch_bounds__(256) void sink_t(const unsigned char* __restrict__ K,
                                              const float* __restrict__ u, float* __restrict__ t_part) {
  int strip = blockIdx.x;  // 64 cols
  int chunk = blockIdx.y;  // 2048 rows
  int p = blockIdx.z;
  int tid = threadIdx.x, w = tid >> 6, lane = tid & 63;
  int rowlane = lane >> 2, cg = lane & 3;
  const unsigned char* Kp = K + (size_t)p * NN * NN + (size_t)chunk * 2048 * NN + strip * 64 + cg * 16;
  __shared__ float ulds[2048];
  const float* up = u + p * NN + chunk * 2048;
  ((f32x4*)ulds)[tid * 2] = ((const f32x4*)up)[tid * 2];
  ((f32x4*)ulds)[tid * 2 + 1] = ((const f32x4*)up)[tid * 2 + 1];
  __syncthreads();
  float ca[16];
#pragma unroll
  for (int j = 0; j < 16; j++) ca[j] = 0.f;
#pragma unroll 4
  for (int it = 0; it < 32; it++) {
    int r = it * 64 + w * 16 + rowlane;
    uint4 k = *(const uint4*)(Kp + (size_t)r * NN);
    float ur = ulds[r];
    float kd[16];
    fp8x16_decode(k, kd);
#pragma unroll
    for (int j = 0; j < 16; j++) ca[j] += kd[j] * ur;
  }
#pragma unroll
  for (int m = 4; m <= 32; m <<= 1)
#pragma unroll
    for (int j = 0; j < 16; j++) ca[j] += __shfl_xor(ca[j], m, 64);
  __shared__ float red[4][64];
  if (rowlane == 0) {
#pragma unroll
    for (int j = 0; j < 16; j++) red[w][cg * 16 + j] = ca[j];
  }
  __syncthreads();
  if (tid < 64)
    t_part[((size_t)chunk * 3 + p) * NN + strip * 64 + tid] =
        red[0][tid] + red[1][tid] + red[2][tid] + red[3][tid];
}

// grid 768 (p*256+rb), block 256, 16 rows/block, single pass:
//   v = nu/(t_part+eps) in vswz; per row: s1=K·v, s2=K·v·lnK; u=mu/(s1+eps) (folded half-step);
//   loss_row = u*(-REG)*s2
__global__ __launch_bounds__(256) void loss_kernel(const unsigned char* __restrict__ K,
                                                   const float* __restrict__ t_part, float* __restrict__ out) {
  int bid = blockIdx.x;
  int p = bid >> 8;
  int rb = bid & 255;
  int tid = threadIdx.x;
  int w = tid >> 6, lane = tid & 63;
  __shared__ float vswz[NN];
  {
    int c = tid >> 6;
#pragma unroll
    for (int q = 0; q < 4; q++) {
      int idx = c * 1024 + lane * 16 + q * 4;
      f32x4 ta = *(const f32x4*)&t_part[(size_t)p * NN + idx];
      f32x4 tb = *(const f32x4*)&t_part[(size_t)(3 + p) * NN + idx];
      f32x4 o;
#pragma unroll
      for (int j = 0; j < 4; j++) o[j] = (1.0f / NN) * __builtin_amdgcn_rcpf(ta[j] + tb[j] + EPSC);
      *(f32x4*)&vswz[((c * 4 + q) * 64 + lane) * 4] = o;
    }
  }
  __syncthreads();
  const unsigned char* Kp = K + (size_t)p * NN * NN;
  int r0 = rb * 16;
  const unsigned char* kbase = Kp + (size_t)(r0 + w * 4) * NN + lane * 16;
  float s1r[4] = {0.f, 0.f, 0.f, 0.f};
  float s2r[4] = {0.f, 0.f, 0.f, 0.f};
#pragma unroll
  for (int c = 0; c < 4; c++) {
    uint4 kr[4];
    kr[0] = *(const uint4*)(kbase + c * 1024);
    kr[1] = *(const uint4*)(kbase + (size_t)NN + c * 1024);
    kr[2] = *(const uint4*)(kbase + (size_t)2 * NN + c * 1024);
    kr[3] = *(const uint4*)(kbase + (size_t)3 * NN + c * 1024);
    f32x4 v0 = *(const f32x4*)&vswz[((c * 4 + 0) * 64 + lane) * 4];
    f32x4 v1 = *(const f32x4*)&vswz[((c * 4 + 1) * 64 + lane) * 4];
    f32x4 v2 = *(const f32x4*)&vswz[((c * 4 + 2) * 64 + lane) * 4];
    f32x4 v3 = *(const f32x4*)&vswz[((c * 4 + 3) * 64 + lane) * 4];
    dot16v_dual(kr[0], v0, v1, v2, v3, s1r[0], s2r[0]);
    dot16v_dual(kr[1], v0, v1, v2, v3, s1r[1], s2r[1]);
    dot16v_dual(kr[2], v0, v1, v2, v3, s1r[2], s2r[2]);
    dot16v_dual(kr[3], v0, v1, v2, v3, s1r[3], s2r[3]);
  }
  float lt = 0.f;
#pragma unroll
  for (int r = 0; r < 4; r++) {
    float s1 = wave_reduce_sum(s1r[r]);
    float s2 = wave_reduce_sum(s2r[r]);
    float u = (1.0f / NN) / (s1 + EPSC);
    lt += u * (-REGC) * s2;
  }
  __shared__ float red[4];
  if (lane == 0) red[w] = lt;
  __syncthreads();
  if (tid == 0) atomicAdd(out, (red[0] + red[1] + red[2] + red[3]) * (1.0f / 3.0f));
}

extern "C" void kernel_launch(void* const* d_in, const int* in_sizes, int n_in,
                              void* d_out, int out_size, void* d_ws, size_t ws_size,
                              hipStream_t stream) {
  const float* z0 = (const float*)d_in[0];
  const float* z1 = (const float*)d_in[1];
  const float* z2 = (const float*)d_in[2];
  float* out = (float*)d_out;
  char* ws = (char*)d_ws;

  const size_t K_BYTES = (size_t)3 * NN * NN;            // 50331648 (fp8)
  unsigned char* K = (unsigned char*)ws;
  short* zb = (short*)(ws + K_BYTES);                    // 3145728 B
  float* sq = (float*)(ws + K_BYTES + 3145728);          // 49152 B
  float* u = (float*)(ws + K_BYTES + 3145728 + 49152);   // 49152 B
  float* cpart = (float*)(ws + K_BYTES + 3145728 + 2 * 49152);   // 1572864 B
  float* t_part = (float*)(ws + K_BYTES + 3145728 + 2 * 49152 + 1572864);  // 2*3*NN*4 = 98304 B

  hipMemsetAsync(d_out, 0, sizeof(float), stream);

  prep_kernel<<<1536, 256, 0, stream>>>(z0, z1, z2, zb, sq);
  kbuild_kernel<<<dim3(32, 32, 3), 256, 0, stream>>>(zb, sq, K, cpart);
  tinit_kernel<<<dim3(16, 3), 256, 0, stream>>>(cpart, t_part);

  for (int it = 0; it < NSINK; it++) {
    sink_u<<<768, 256, 0, stream>>>(K, t_part, u);
    sink_t<<<dim3(64, 2, 3), 256, 0, stream>>>(K, u, t_part);
  }
  // loss recomputes v from the final t_part and folds the last u-half-step
  loss_kernel<<<768, 256, 0, stream>>>(K, t_part, out);
}

// Round 12
// 179.867 us; speedup vs baseline: 1.3712x; 1.1452x over previous
//
#include <hip/hip_runtime.h>

#define NN 4096
#define DD 128
#define REGC 0.05f
#define EPSC 1e-8f
#define KPAD2 136   // shorts; 272B row stride, keeps 16B row alignment

typedef float f32x4 __attribute__((ext_vector_type(4)));
typedef float f32x2 __attribute__((ext_vector_type(2)));
typedef short s16x8 __attribute__((ext_vector_type(8)));
typedef short s16x4 __attribute__((ext_vector_type(4)));

__device__ __forceinline__ float wave_reduce_sum(float s) {
#pragma unroll
  for (int m = 32; m >= 1; m >>= 1) s += __shfl_xor(s, m, 64);
  return s;
}

__device__ __forceinline__ short f32_to_bf16(float f) {
  union { float f; unsigned u; } x; x.f = f;
  unsigned r = (x.u + 0x7FFFu + ((x.u >> 16) & 1u)) >> 16;
  return (short)r;
}

__device__ __forceinline__ void fp8x4_decode(unsigned int k, float* o) {
  f32x2 lo = __builtin_amdgcn_cvt_pk_f32_fp8((int)k, false);
  f32x2 hi = __builtin_amdgcn_cvt_pk_f32_fp8((int)k, true);
  o[0] = lo[0]; o[1] = lo[1]; o[2] = hi[0]; o[3] = hi[1];
}

__device__ __forceinline__ void fp8x16_decode(uint4 k, float* o) {
  fp8x4_decode(k.x, o); fp8x4_decode(k.y, o + 4);
  fp8x4_decode(k.z, o + 8); fp8x4_decode(k.w, o + 12);
}

__device__ __forceinline__ float dot16v(uint4 k, f32x4 v0, f32x4 v1, f32x4 v2, f32x4 v3) {
  float o[16];
  fp8x16_decode(k, o);
  float s = 0.f;
#pragma unroll
  for (int j = 0; j < 4; j++) s += o[j] * v0[j];
#pragma unroll
  for (int j = 0; j < 4; j++) s += o[4 + j] * v1[j];
#pragma unroll
  for (int j = 0; j < 4; j++) s += o[8 + j] * v2[j];
#pragma unroll
  for (int j = 0; j < 4; j++) s += o[12 + j] * v3[j];
  return s;
}

// grid 1536, block 256: 8 rows/block, 32 lanes/row, f32x4 loads; row norms + bf16 convert
__global__ __launch_bounds__(256) void prep_kernel(const float* __restrict__ z0, const float* __restrict__ z1,
                                                   const float* __restrict__ z2, short* __restrict__ zb,
                                                   float* __restrict__ sq) {
  int tid = threadIdx.x;
  int row = blockIdx.x * 8 + (tid >> 5);
  int e = (tid & 31) * 4;
  int zi = row >> 12;
  const float* z = (zi == 0) ? z0 : ((zi == 1) ? z1 : z2);
  int r = row & (NN - 1);
  f32x4 val = *(const f32x4*)&z[r * DD + e];
  s16x4 b;
#pragma unroll
  for (int j = 0; j < 4; j++) b[j] = f32_to_bf16(val[j]);
  *(s16x4*)&zb[row * DD + e] = b;
  float s = val[0] * val[0] + val[1] * val[1] + val[2] * val[2] + val[3] * val[3];
#pragma unroll
  for (int m = 16; m >= 1; m >>= 1) s += __shfl_xor(s, m, 64);
  if ((tid & 31) == 0) sq[row] = s;
}

// grid dim3(32,32,3), block 256. Computes K = fp8(exp(-C/reg)) AND Lp = fp8(K * C/REG)
// (= -K lnK, exact — no log). Both bounced through padded LDS tiles for full-line stores.
// Col sums of K -> cpart[(p*32+by)*NN + bx*128+col].
__global__ __launch_bounds__(256, 3) void kbuild_kernel(const short* __restrict__ zb, const float* __restrict__ sq,
                                                        unsigned char* __restrict__ K, unsigned char* __restrict__ Lp,
                                                        float* __restrict__ cpart) {
  int p = blockIdx.z;
  int ai = (p == 2) ? 1 : 0;            // pairs (0,1),(0,2),(1,2)
  int bi = (p == 0) ? 1 : 2;
  const short* xg = zb + ai * NN * DD + blockIdx.y * 128 * DD;   // B operand (K rows)
  const short* yg = zb + bi * NN * DD + blockIdx.x * 128 * DD;   // A operand (K cols), staged
  const float* sqx = sq + ai * NN + blockIdx.y * 128;
  const float* sqy = sq + bi * NN + blockIdx.x * 128;
  __shared__ __align__(16) unsigned char smem[36864];  // ys (34816B) aliased by ktK+ktL (2x18432B)
  __shared__ float colsum[128];
  short* ys = (short*)smem;
  unsigned int* ktK = (unsigned int*)smem;               // [128][36] u32
  unsigned int* ktL = (unsigned int*)(smem + 18432);     // [128][36] u32
  int tid = threadIdx.x;
  for (int i = tid; i < 2048; i += 256) {
    int row = i >> 4, seg = i & 15;
    *(uint4*)&ys[row * KPAD2 + seg * 8] = *(const uint4*)&yg[row * DD + seg * 8];
  }
  if (tid < 128) colsum[tid] = 0.f;
  __syncthreads();
  int w = tid >> 6, lane = tid & 63;
  int wy = (w >> 1) * 64, wx = (w & 1) * 64;   // y(col) / x(row) quadrants
  int lrow = lane & 15, lk = lane >> 4;
  f32x4 acc[4][4];   // [yt][xt]
#pragma unroll
  for (int i = 0; i < 4; i++)
#pragma unroll
    for (int j = 0; j < 4; j++) acc[i][j] = (f32x4){0.f, 0.f, 0.f, 0.f};
#pragma unroll
  for (int kk = 0; kk < 4; kk++) {
    s16x8 a[4], b[4];
#pragma unroll
    for (int t = 0; t < 4; t++) {
      a[t] = *(const s16x8*)&ys[(wy + t * 16 + lrow) * KPAD2 + kk * 32 + lk * 8];
      b[t] = *(const s16x8*)&xg[(wx + t * 16 + lrow) * DD + kk * 32 + lk * 8];
    }
#pragma unroll
    for (int yt = 0; yt < 4; yt++)
#pragma unroll
      for (int xt = 0; xt < 4; xt++)
        acc[yt][xt] = __builtin_amdgcn_mfma_f32_16x16x32_bf16(a[yt], b[xt], acc[yt][xt], 0, 0, 0);
  }
  // D layout: lane&15 -> x (K-row); (lane>>4)*4+reg -> y (K-col)
  unsigned int pk[4][4], pl[4][4];   // [xt][yt] packed 4 consecutive K-cols
  float csum[4][4];                  // [yt][r]
#pragma unroll
  for (int i = 0; i < 4; i++)
#pragma unroll
    for (int j = 0; j < 4; j++) csum[i][j] = 0.f;
#pragma unroll
  for (int xt = 0; xt < 4; xt++) {
    int xl = wx + xt * 16 + lrow;
    float sx = sqx[xl];
#pragma unroll
    for (int yt = 0; yt < 4; yt++) {
      int yl0 = wy + yt * 16 + lk * 4;
      float kf[4], lf[4];
#pragma unroll
      for (int r = 0; r < 4; r++) {
        float Cv = fmaxf(sx + sqy[yl0 + r] - 2.0f * acc[yt][xt][r], 0.0f);
        kf[r] = __expf(Cv * (-1.0f / REGC));
        lf[r] = kf[r] * (Cv * (1.0f / REGC));   // = -K lnK, exact
        csum[yt][r] += kf[r];
      }
      int pwk = __builtin_amdgcn_cvt_pk_fp8_f32(kf[0], kf[1], 0, false);
      pwk = __builtin_amdgcn_cvt_pk_fp8_f32(kf[2], kf[3], pwk, true);
      pk[xt][yt] = (unsigned int)pwk;
      int pwl = __builtin_amdgcn_cvt_pk_fp8_f32(lf[0], lf[1], 0, false);
      pwl = __builtin_amdgcn_cvt_pk_fp8_f32(lf[2], lf[3], pwl, true);
      pl[xt][yt] = (unsigned int)pwl;
    }
  }
#pragma unroll
  for (int yt = 0; yt < 4; yt++)
#pragma unroll
    for (int r = 0; r < 4; r++) {
      float s = csum[yt][r];
      s += __shfl_xor(s, 1, 64); s += __shfl_xor(s, 2, 64);
      s += __shfl_xor(s, 4, 64); s += __shfl_xor(s, 8, 64);
      if (lrow == 0) atomicAdd(&colsum[wy + yt * 16 + lk * 4 + r], s);
    }
  __syncthreads();   // done reading ys; safe to alias with ktK/ktL
#pragma unroll
  for (int xt = 0; xt < 4; xt++) {
    int xl = wx + xt * 16 + lrow;
#pragma unroll
    for (int yt = 0; yt < 4; yt++) {
      int wi = xl * 36 + ((wy + yt * 16) >> 2) + lk;
      ktK[wi] = pk[xt][yt];
      ktL[wi] = pl[xt][yt];
    }
  }
  __syncthreads();
  size_t toff = (size_t)p * NN * NN + (size_t)blockIdx.y * 128 * NN + blockIdx.x * 128;
  unsigned char* Kb = K + toff;
  unsigned char* Lb = Lp + toff;
#pragma unroll
  for (int rd = 0; rd < 4; rd++) {
    int rl = (tid >> 3) + rd * 32;
    int ch = tid & 7;
    *(uint4*)(Kb + (size_t)rl * NN + ch * 16) = *(const uint4*)&ktK[rl * 36 + ch * 4];
    *(uint4*)(Lb + (size_t)rl * NN + ch * 16) = *(const uint4*)&ktL[rl * 36 + ch * 4];
  }
  if (tid < 128)
    cpart[(size_t)(p * 32 + blockIdx.y) * NN + blockIdx.x * 128 + tid] = colsum[tid];
}

// grid dim3(16,3), block 256: t_part chunk0 = sum_by cpart (= K^T 1), chunk1 = 0
__global__ __launch_bounds__(256) void tinit_kernel(const float* __restrict__ cpart, float* __restrict__ t_part) {
  int p = blockIdx.y;
  int col = blockIdx.x * 256 + threadIdx.x;
  float s = 0.f;
#pragma unroll 8
  for (int by = 0; by < 32; by++) s += cpart[(size_t)(p * 32 + by) * NN + col];
  t_part[(size_t)p * NN + col] = s;
  t_part[(size_t)(3 + p) * NN + col] = 0.f;
}

// grid 768 (p*256+rb), block 256, 16 rows/block:
//   A: v = nu/(t_part[0]+t_part[1]+eps) -> LDS (swizzled)
//   B: u = mu/(K v + eps) for the block's 16 rows (4 rows/wave)
__global__ __launch_bounds__(256) void sink_u(const unsigned char* __restrict__ K,
                                              const float* __restrict__ t_part, float* __restrict__ u) {
  int bid = blockIdx.x;
  int p = bid >> 8;
  int rb = bid & 255;
  int tid = threadIdx.x;
  int w = tid >> 6, lane = tid & 63;
  __shared__ float vswz[NN];   // v[col], col = c*1024 + lane*16 + q*4 + j at [((c*4+q)*64+lane)*4+j]
  {
    int c = tid >> 6;
#pragma unroll
    for (int q = 0; q < 4; q++) {
      int idx = c * 1024 + lane * 16 + q * 4;
      f32x4 ta = *(const f32x4*)&t_part[(size_t)p * NN + idx];
      f32x4 tb = *(const f32x4*)&t_part[(size_t)(3 + p) * NN + idx];
      f32x4 o;
#pragma unroll
      for (int j = 0; j < 4; j++) o[j] = (1.0f / NN) * __builtin_amdgcn_rcpf(ta[j] + tb[j] + EPSC);
      *(f32x4*)&vswz[((c * 4 + q) * 64 + lane) * 4] = o;
    }
  }
  __syncthreads();
  const unsigned char* Kp = K + (size_t)p * NN * NN;
  int r0 = rb * 16;
  const unsigned char* kbase = Kp + (size_t)(r0 + w * 4) * NN + lane * 16;
  float acc0 = 0.f, acc1 = 0.f, acc2 = 0.f, acc3 = 0.f;
#pragma unroll
  for (int c = 0; c < 4; c++) {
    uint4 k0 = *(const uint4*)(kbase + c * 1024);
    uint4 k1 = *(const uint4*)(kbase + (size_t)NN + c * 1024);
    uint4 k2 = *(const uint4*)(kbase + (size_t)2 * NN + c * 1024);
    uint4 k3 = *(const uint4*)(kbase + (size_t)3 * NN + c * 1024);
    f32x4 v0 = *(const f32x4*)&vswz[((c * 4 + 0) * 64 + lane) * 4];
    f32x4 v1 = *(const f32x4*)&vswz[((c * 4 + 1) * 64 + lane) * 4];
    f32x4 v2 = *(const f32x4*)&vswz[((c * 4 + 2) * 64 + lane) * 4];
    f32x4 v3 = *(const f32x4*)&vswz[((c * 4 + 3) * 64 + lane) * 4];
    acc0 += dot16v(k0, v0, v1, v2, v3);
    acc1 += dot16v(k1, v0, v1, v2, v3);
    acc2 += dot16v(k2, v0, v1, v2, v3);
    acc3 += dot16v(k3, v0, v1, v2, v3);
  }
  acc0 = wave_reduce_sum(acc0);
  acc1 = wave_reduce_sum(acc1);
  acc2 = wave_reduce_sum(acc2);
  acc3 = wave_reduce_sum(acc3);
  if (lane == 0) {
    float* ug = u + p * NN + r0 + w * 4;
    ug[0] = (1.0f / NN) / (acc0 + EPSC);
    ug[1] = (1.0f / NN) / (acc1 + EPSC);
    ug[2] = (1.0f / NN) / (acc2 + EPSC);
    ug[3] = (1.0f / NN) / (acc3 + EPSC);
  }
}

// grid dim3(64,2,3), block 256: column pass, NO atomics.
// t_part[(chunk*3+p)*NN + cols] = sum over chunk's 2048 rows of K[row][col]*u[row]
__global__ __launch_bounds__(256) void sink_t(const unsigned char* __restrict__ K,
                                              const float* __restrict__ u, float* __restrict__ t_part) {
  int strip = blockIdx.x;  // 64 cols
  int chunk = blockIdx.y;  // 2048 rows
  int p = blockIdx.z;
  int tid = threadIdx.x, w = tid >> 6, lane = tid & 63;
  int rowlane = lane >> 2, cg = lane & 3;
  const unsigned char* Kp = K + (size_t)p * NN * NN + (size_t)chunk * 2048 * NN + strip * 64 + cg * 16;
  __shared__ float ulds[2048];
  const float* up = u + p * NN + chunk * 2048;
  ((f32x4*)ulds)[tid * 2] = ((const f32x4*)up)[tid * 2];
  ((f32x4*)ulds)[tid * 2 + 1] = ((const f32x4*)up)[tid * 2 + 1];
  __syncthreads();
  float ca[16];
#pragma unroll
  for (int j = 0; j < 16; j++) ca[j] = 0.f;
#pragma unroll 4
  for (int it = 0; it < 32; it++) {
    int r = it * 64 + w * 16 + rowlane;
    uint4 k = *(const uint4*)(Kp + (size_t)r * NN);
    float ur = ulds[r];
    float kd[16];
    fp8x16_decode(k, kd);
#pragma unroll
    for (int j = 0; j < 16; j++) ca[j] += kd[j] * ur;
  }
#pragma unroll
  for (int m = 4; m <= 32; m <<= 1)
#pragma unroll
    for (int j = 0; j < 16; j++) ca[j] += __shfl_xor(ca[j], m, 64);
  __shared__ float red[4][64];
  if (rowlane == 0) {
#pragma unroll
    for (int j = 0; j < 16; j++) red[w][cg * 16 + j] = ca[j];
  }
  __syncthreads();
  if (tid < 64)
    t_part[((size_t)chunk * 3 + p) * NN + strip * 64 + tid] =
        red[0][tid] + red[1][tid] + red[2][tid] + red[3][tid];
}

// grid 768 (p*256+rb), block 256, 16 rows/block, single pass over Lp (= -K lnK):
//   v = nu/(t_part+eps) in vswz; per row: s2 = Lp·v; loss += REG * u_i * s2_i  (C = -REG lnK)
__global__ __launch_bounds__(256) void loss_kernel(const unsigned char* __restrict__ Lp,
                                                   const float* __restrict__ t_part, const float* __restrict__ u,
                                                   float* __restrict__ out) {
  int bid = blockIdx.x;
  int p = bid >> 8;
  int rb = bid & 255;
  int tid = threadIdx.x;
  int w = tid >> 6, lane = tid & 63;
  __shared__ float vswz[NN];
  {
    int c = tid >> 6;
#pragma unroll
    for (int q = 0; q < 4; q++) {
      int idx = c * 1024 + lane * 16 + q * 4;
      f32x4 ta = *(const f32x4*)&t_part[(size_t)p * NN + idx];
      f32x4 tb = *(const f32x4*)&t_part[(size_t)(3 + p) * NN + idx];
      f32x4 o;
#pragma unroll
      for (int j = 0; j < 4; j++) o[j] = (1.0f / NN) * __builtin_amdgcn_rcpf(ta[j] + tb[j] + EPSC);
      *(f32x4*)&vswz[((c * 4 + q) * 64 + lane) * 4] = o;
    }
  }
  __syncthreads();
  const unsigned char* Lb = Lp + (size_t)p * NN * NN;
  int r0 = rb * 16;
  const unsigned char* kbase = Lb + (size_t)(r0 + w * 4) * NN + lane * 16;
  float acc0 = 0.f, acc1 = 0.f, acc2 = 0.f, acc3 = 0.f;
#pragma unroll
  for (int c = 0; c < 4; c++) {
    uint4 k0 = *(const uint4*)(kbase + c * 1024);
    uint4 k1 = *(const uint4*)(kbase + (size_t)NN + c * 1024);
    uint4 k2 = *(const uint4*)(kbase + (size_t)2 * NN + c * 1024);
    uint4 k3 = *(const uint4*)(kbase + (size_t)3 * NN + c * 1024);
    f32x4 v0 = *(const f32x4*)&vswz[((c * 4 + 0) * 64 + lane) * 4];
    f32x4 v1 = *(const f32x4*)&vswz[((c * 4 + 1) * 64 + lane) * 4];
    f32x4 v2 = *(const f32x4*)&vswz[((c * 4 + 2) * 64 + lane) * 4];
    f32x4 v3 = *(const f32x4*)&vswz[((c * 4 + 3) * 64 + lane) * 4];
    acc0 += dot16v(k0, v0, v1, v2, v3);
    acc1 += dot16v(k1, v0, v1, v2, v3);
    acc2 += dot16v(k2, v0, v1, v2, v3);
    acc3 += dot16v(k3, v0, v1, v2, v3);
  }
  acc0 = wave_reduce_sum(acc0);
  acc1 = wave_reduce_sum(acc1);
  acc2 = wave_reduce_sum(acc2);
  acc3 = wave_reduce_sum(acc3);
  float lt = 0.f;
  if (lane == 0) {
    const float* ug = u + p * NN + r0 + w * 4;
    lt = acc0 * ug[0] + acc1 * ug[1] + acc2 * ug[2] + acc3 * ug[3];
  }
  __shared__ float red[4];
  if (lane == 0) red[w] = lt;
  __syncthreads();
  if (tid == 0)
    atomicAdd(out, (red[0] + red[1] + red[2] + red[3]) * (REGC / 3.0f));
}

extern "C" void kernel_launch(void* const* d_in, const int* in_sizes, int n_in,
                              void* d_out, int out_size, void* d_ws, size_t ws_size,
                              hipStream_t stream) {
  const float* z0 = (const float*)d_in[0];
  const float* z1 = (const float*)d_in[1];
  const float* z2 = (const float*)d_in[2];
  float* out = (float*)d_out;
  char* ws = (char*)d_ws;

  const size_t K_BYTES = (size_t)3 * NN * NN;            // 50331648 (fp8)
  unsigned char* K = (unsigned char*)ws;
  unsigned char* Lp = (unsigned char*)(ws + K_BYTES);    // second 48 MB: -K lnK
  char* base = ws + 2 * K_BYTES;
  short* zb = (short*)base;                              // 3145728 B
  float* sq = (float*)(base + 3145728);                  // 49152 B
  float* u = (float*)(base + 3145728 + 49152);           // 49152 B
  float* cpart = (float*)(base + 3145728 + 2 * 49152);   // 1572864 B
  float* t_part = (float*)(base + 3145728 + 2 * 49152 + 1572864);  // 98304 B

  hipMemsetAsync(d_out, 0, sizeof(float), stream);

  prep_kernel<<<1536, 256, 0, stream>>>(z0, z1, z2, zb, sq);
  kbuild_kernel<<<dim3(32, 32, 3), 256, 0, stream>>>(zb, sq, K, Lp, cpart);
  tinit_kernel<<<dim3(16, 3), 256, 0, stream>>>(cpart, t_part);   // t1 (u0 = 1)

  sink_u<<<768, 256, 0, stream>>>(K, t_part, u);                  // v1, u1
  sink_t<<<dim3(64, 2, 3), 256, 0, stream>>>(K, u, t_part);       // t2
  sink_u<<<768, 256, 0, stream>>>(K, t_part, u);                  // v2, u2 (consistent pair)

  // loss = REG * sum_i u2_i * (Lp v2)_i  with v2 recomputed from t2
  loss_kernel<<<768, 256, 0, stream>>>(Lp, t_part, u, out);
}